// Round 2
// baseline (3299.887 us; speedup 1.0000x reference)
//
#include <hip/hip_runtime.h>

typedef _Float16 half_t;
typedef half_t half8 __attribute__((ext_vector_type(8)));
typedef half_t half4 __attribute__((ext_vector_type(4)));
typedef float  floatx4 __attribute__((ext_vector_type(4)));

#define NB 2048
#define NT 20
#define CD 512
#define HD 1024
#define VD 2048
#define QD 1024
#define KS 32   // K-step (halves)

// All GEMM tiles: BM=64 rows, K-step 32. LDS layout per buffer: A tile
// 64x32 linear + NG weight tiles BNx32 linear. 3-buffer ring, depth-2
// prefetch with counted vmcnt (T4): s_waitcnt vmcnt(L) -> s_barrier ->
// issue stage(s+2) -> MFMA. No vmcnt(0) drain in the main loop.
// Bank-conflict fix for 32-col (64 B) rows: chunk ^= (row>>1)&3 gives the
// optimal 2-way aliasing (free, m136); applied by pre-swizzling the GLOBAL
// source address so global_load_lds dests stay lane-linear (m104/m173).

__device__ __forceinline__ float sigmoidf_(float x) { return 1.0f / (1.0f + __expf(-x)); }
__device__ __forceinline__ float tanhf_(float x)    { return 1.0f - 2.0f / (1.0f + __expf(2.0f * x)); }
__device__ __forceinline__ float lrelu_(float x)    { return x > 0.0f ? x : 0.01f * x; }

template <int N> __device__ __forceinline__ void waitv() {
    asm volatile("s_waitcnt vmcnt(%0)" :: "n"(N) : "memory");
}

__device__ __forceinline__ void gload16(const half_t* g, half_t* l) {
    __builtin_amdgcn_global_load_lds(
        (const __attribute__((address_space(1))) void*)g,
        (__attribute__((address_space(3))) void*)l, 16, 0, 0);
}

// All role-grids are 16 x 32 blocks. XCD-aware remap: the 8 XCDs each own 2
// weight-column blocks so the per-XCD weight slice stays L2-resident over t.
__device__ __forceinline__ void remap512(int bx, int by, int bn, int& m0, int& c0) {
    const int flat = by * 16 + bx;
    const int xcd = flat & 7, i = flat >> 3;
    c0 = (xcd * 2 + (i >> 5)) * bn;
    m0 = (i & 31) * 64;
}

template <int NG, int BN, int NACC, int I0, int I1, int I2>
__device__ __forceinline__ void compute_step(
    const half_t* lb, floatx4 (&acc)[NACC][2][BN / 32],
    int frow, int cg, int wr, int wc)
{
    constexpr int NIN = BN / 32;
    constexpr int map_[3] = {I0, I1, I2};
    half8 af[2];
#pragma unroll
    for (int im = 0; im < 2; ++im) {
        const int r = wr + im * 16 + frow;
        af[im] = *(const half8*)(lb + r * KS + ((cg ^ ((r >> 1) & 3)) * 8));
    }
#pragma unroll
    for (int g = 0; g < NG; ++g)
#pragma unroll
        for (int in = 0; in < NIN; ++in) {
            const int r = wc + in * 16 + frow;
            const half8 bf = *(const half8*)(lb + 64 * KS + g * (BN * KS) + r * KS +
                                             ((cg ^ ((r >> 1) & 3)) * 8));
#pragma unroll
            for (int im = 0; im < 2; ++im)
                acc[map_[g]][im][in] = __builtin_amdgcn_mfma_f32_16x16x32_f16(
                    af[im], bf, acc[map_[g]][im][in], 0, 0, 0);
        }
}

// Dual-phase GEMM with 3-buffer ring + counted vmcnt.
// acc[mapA[g]] += A1[64xK1] @ W1_g^T  then  acc[mapB[g]] += A2[64xK2] @ W2_g^T.
// WL = W-tile 16B-chunk loads per thread per stage (duplicated slots are
// benign rewrites of identical bytes, kept so vmcnt counts stay wave-uniform).
template <int NG, int BN, int WL, int NACC,
          int I0A, int I1A, int I2A, int I0B, int I1B, int I2B>
__device__ __forceinline__ void gemm_ring(
    const half_t* __restrict__ A1, int lda1, const half_t* __restrict__ W1, long gs1, int S1,
    const half_t* __restrict__ A2, int lda2, const half_t* __restrict__ W2, long gs2, int S2,
    int m0, int c0, half_t* lds, floatx4 (&acc)[NACC][2][BN / 32])
{
    constexpr int ASZ = 64 * KS;                 // A tile halves
    constexpr int WSL = NG * BN * 4;             // W tile 16B slots
    constexpr int BUFSZ = ASZ + NG * BN * KS;    // halves per ring buffer
    constexpr int LPT = 1 + WL;                  // vmem issues per thread per stage

    const int tid  = threadIdx.x;
    const int lane = tid & 63;
    const int wid  = tid >> 6;
    const int wr   = (wid >> 1) * 32;
    const int wc   = (wid & 1) * (BN / 2);
    const int frow = lane & 15;
    const int cg   = lane >> 4;

    // s-invariant staging maps (source pre-swizzled; dest lane-linear)
    const int arow = tid >> 2;
    const int aq   = ((tid & 3) ^ ((arow >> 1) & 3)) * 8;
    const long aoff1 = (long)(m0 + arow) * lda1 + aq;
    const long aoff2 = (long)(m0 + arow) * lda2 + aq;

    int  wdst[WL];
    long woff1[WL], woff2[WL];
#pragma unroll
    for (int j = 0; j < WL; ++j) {
        int u = tid + j * 256; if (u >= WSL) u -= WSL;
        const int g   = u / (BN * 4);
        const int idx = u - g * (BN * 4);
        const int row = idx >> 2;
        const int q   = ((idx & 3) ^ ((row >> 1) & 3)) * 8;
        wdst[j]  = ASZ + u * 8;
        woff1[j] = (long)g * gs1 + (long)(c0 + row) * (S1 * KS) + q;
        woff2[j] = (long)g * gs2 + (long)(c0 + row) * (S2 * KS) + q;
    }

    const int S = S1 + S2;
    auto stage = [&](int s) {
        half_t* lb = lds + (s % 3) * BUFSZ;
        if (s < S1) {
            const int k0 = s * KS;
            gload16(A1 + aoff1 + k0, lb + tid * 8);
#pragma unroll
            for (int j = 0; j < WL; ++j) gload16(W1 + woff1[j] + k0, lb + wdst[j]);
        } else {
            const int k0 = (s - S1) * KS;
            gload16(A2 + aoff2 + k0, lb + tid * 8);
#pragma unroll
            for (int j = 0; j < WL; ++j) gload16(W2 + woff2[j] + k0, lb + wdst[j]);
        }
    };

    stage(0); stage(1);
    for (int s = 0; s < S; ++s) {
        // drain our own stage(s) loads (leave stage(s+1) in flight), then the
        // barrier guarantees every wave's stage(s) contribution has landed.
        if (s + 1 < S) waitv<LPT>(); else waitv<0>();
        __builtin_amdgcn_s_barrier();
        if (s + 2 < S) stage(s + 2);   // overwrites buf[(s-1)%3]: all waves are past compute(s-1)
        const half_t* lb = lds + (s % 3) * BUFSZ;
        if (s < S1) compute_step<NG, BN, NACC, I0A, I1A, I2A>(lb, acc, frow, cg, wr, wc);
        else        compute_step<NG, BN, NACC, I0B, I1B, I2B>(lb, acc, frow, cg, wr, wc);
    }
}

// ---- fused fp32->fp16 conversion of all 10 buffers in one launch ----
struct CvtArgs {
    const float* src[10];
    half_t* dst[10];
    int start[11];                      // block prefix offsets
};
__global__ void cvt_all_kernel(CvtArgs a) {
    const int b = blockIdx.x;
    int i = 0;
#pragma unroll
    for (int k = 0; k < 9; ++k) i += (b >= a.start[k + 1]);
    const int idx = ((b - a.start[i]) * 256 + (int)threadIdx.x) * 4;
    float4 f = *(const float4*)(a.src[i] + idx);
    half4 h = {(half_t)f.x, (half_t)f.y, (half_t)f.z, (half_t)f.w};
    *(half4*)(a.dst[i] + idx) = h;
}

// fvq = leaky(v@Wv^T) + leaky(q@Wq^T)   [NB, CD] fp32.  BN=32, grid 16x32.
__global__ __launch_bounds__(256, 2) void fvq_kernel(
    const half_t* __restrict__ v_h, const half_t* __restrict__ wv_w,
    const half_t* __restrict__ q_h, const half_t* __restrict__ wq_w,
    float* __restrict__ fvq)
{
    __shared__ half_t lds[3 * (64 * KS + 32 * KS)];
    floatx4 acc[2][2][1];
#pragma unroll
    for (int g = 0; g < 2; ++g) for (int im = 0; im < 2; ++im)
        acc[g][im][0] = (floatx4){0.f, 0.f, 0.f, 0.f};
    int m0, c0; remap512(blockIdx.x, blockIdx.y, 32, m0, c0);
    gemm_ring<1, 32, 1, 2, 0, 0, 0, 1, 0, 0>(
        v_h, VD, wv_w, 0, VD / KS, q_h, QD, wq_w, 0, QD / KS, m0, c0, lds, acc);

    const int lane = threadIdx.x & 63;
    const int wid = threadIdx.x >> 6;
    const int wr = (wid >> 1) * 32, wc = (wid & 1) * 16;
#pragma unroll
    for (int im = 0; im < 2; ++im) {
        const int mb = m0 + wr + im * 16 + (lane >> 4) * 4;
        const int c  = c0 + wc + (lane & 15);
#pragma unroll
        for (int j = 0; j < 4; ++j)
            fvq[(mb + j) * CD + c] = lrelu_(acc[0][im][0][j]) + lrelu_(acc[1][im][0][j]);
    }
}

// step1 body: h1' = GRUCell(x_t, h1); att = sigmoid(h1'*fvq)*x_t; alphas.
// acc: 0 = i_r+h_r, 1 = i_z+h_z, 2 = i_n, 3 = h_n.  BN=32, role-grid 16x32.
__device__ __forceinline__ void step1_body(
    int bx, int by,
    const half_t* __restrict__ cap_h,
    const half_t* __restrict__ wih1, const half_t* __restrict__ whh1,
    const float* __restrict__ b_ih1, const float* __restrict__ b_hh1,
    const half_t* __restrict__ h1_src, half_t* __restrict__ h1_dst,
    const float* __restrict__ fvq, const float* __restrict__ caption,
    const int* __restrict__ cap_len,
    half_t* __restrict__ att_h, float* __restrict__ alphas, int t, half_t* lds)
{
    floatx4 acc[4][2][1];
#pragma unroll
    for (int g = 0; g < 4; ++g) for (int im = 0; im < 2; ++im)
        acc[g][im][0] = (floatx4){0.f, 0.f, 0.f, 0.f};
    int m0, c0; remap512(bx, by, 32, m0, c0);
    gemm_ring<3, 32, 2, 4, 0, 1, 2, 0, 1, 3>(
        cap_h + t * CD, NT * CD, wih1, (long)CD * CD, CD / KS,
        h1_src, CD, whh1, (long)CD * CD, CD / KS, m0, c0, lds, acc);

    const int lane = threadIdx.x & 63;
    const int wid = threadIdx.x >> 6;
    const int wr = (wid >> 1) * 32, wc = (wid & 1) * 16;
#pragma unroll
    for (int im = 0; im < 2; ++im) {
        const int mb = m0 + wr + im * 16 + (lane >> 4) * 4;
        const int c  = c0 + wc + (lane & 15);
        const float br = b_ih1[c] + b_hh1[c];
        const float bz = b_ih1[CD + c] + b_hh1[CD + c];
        const float bin_ = b_ih1[2 * CD + c];
        const float bhn  = b_hh1[2 * CD + c];
#pragma unroll
        for (int j = 0; j < 4; ++j) {
            const int m = mb + j;
            const float r = sigmoidf_(acc[0][im][0][j] + br);
            const float z = sigmoidf_(acc[1][im][0][j] + bz);
            const float n = tanhf_(acc[2][im][0][j] + bin_ + r * (acc[3][im][0][j] + bhn));
            const float h_old = (float)h1_src[m * CD + c];
            const bool act = t < cap_len[m];
            const float h_new = act ? ((1.f - z) * n + z * h_old) : h_old;
            const float x = caption[(m * NT + t) * CD + c];
            const float at = sigmoidf_(h_new * fvq[m * CD + c]) * x;
            h1_dst[m * CD + c] = (half_t)h_new;
            att_h[m * CD + c]  = (half_t)at;
            alphas[(m * NT + t) * CD + c] = act ? at : 0.f;
        }
    }
}

// step3 body: out = max(out, active ? leaky(h2 @ Wfc^T) : skip). BN=64.
__device__ __forceinline__ void step3_body(
    int bx, int by,
    const half_t* __restrict__ h2_cur, const half_t* __restrict__ wfc,
    const int* __restrict__ cap_len, float* __restrict__ outmax, int t, half_t* lds)
{
    floatx4 acc[1][2][2];
#pragma unroll
    for (int im = 0; im < 2; ++im) for (int in = 0; in < 2; ++in)
        acc[0][im][in] = (floatx4){0.f, 0.f, 0.f, 0.f};
    int m0, c0; remap512(bx, by, 64, m0, c0);
    gemm_ring<1, 64, 1, 1, 0, 0, 0, 0, 0, 0>(
        h2_cur, HD, wfc, 0, HD / KS,
        h2_cur, HD, wfc, 0, 0, m0, c0, lds, acc);

    const int lane = threadIdx.x & 63;
    const int wid = threadIdx.x >> 6;
    const int wr = (wid >> 1) * 32, wc = (wid & 1) * 32;
#pragma unroll
    for (int im = 0; im < 2; ++im)
#pragma unroll
    for (int in = 0; in < 2; ++in) {
        const int mb = m0 + wr + im * 16 + (lane >> 4) * 4;
        const int c  = c0 + wc + in * 16 + (lane & 15);
#pragma unroll
        for (int j = 0; j < 4; ++j) {
            const int m = mb + j;
            if (t < cap_len[m]) {
                const float v0 = lrelu_(acc[0][im][in][j]);
                float* p = &outmax[m * HD + c];
                *p = fmaxf(*p, v0);
            }
        }
    }
}

__global__ __launch_bounds__(256, 2) void step1_kernel(
    const half_t* cap_h, const half_t* wih1, const half_t* whh1,
    const float* b_ih1, const float* b_hh1,
    const half_t* h1_src, half_t* h1_dst, const float* fvq,
    const float* caption, const int* cap_len,
    half_t* att_h, float* alphas, int t)
{
    __shared__ half_t lds[3 * (64 * KS + 3 * 32 * KS)];
    step1_body(blockIdx.x, blockIdx.y, cap_h, wih1, whh1, b_ih1, b_hh1,
               h1_src, h1_dst, fvq, caption, cap_len, att_h, alphas, t, lds);
}

__global__ __launch_bounds__(256, 2) void step3_kernel(
    const half_t* h2_cur, const half_t* wfc, const int* cap_len,
    float* outmax, int t)
{
    __shared__ half_t lds[3 * (64 * KS + 64 * KS)];
    step3_body(blockIdx.x, blockIdx.y, h2_cur, wfc, cap_len, outmax, t, lds);
}

// fused: step3(t3) on blocks y<32, step1(t1 = t3+1) on blocks y>=32.
// The two are data-independent; co-scheduling fills the machine (4 blocks/CU).
__global__ __launch_bounds__(256, 4) void fused31_kernel(
    const half_t* h2_cur, const half_t* wfc, const int* cap_len,
    float* outmax, int t3,
    const half_t* cap_h, const half_t* wih1, const half_t* whh1,
    const float* b_ih1, const float* b_hh1,
    const half_t* h1_src, half_t* h1_dst, const float* fvq,
    const float* caption, half_t* att_h, float* alphas, int t1)
{
    __shared__ half_t lds[3 * (64 * KS + 3 * 32 * KS)];   // max(step1 30KB, step3 24KB)
    if (blockIdx.y < 32)
        step3_body(blockIdx.x, blockIdx.y, h2_cur, wfc, cap_len, outmax, t3, lds);
    else
        step1_body(blockIdx.x, blockIdx.y - 32, cap_h, wih1, whh1, b_ih1, b_hh1,
                   h1_src, h1_dst, fvq, caption, cap_len, att_h, alphas, t1, lds);
}

// step 2: h2' = GRUCell(att, h2).  BN=64, grid 16x32, 48KB ring.
__global__ __launch_bounds__(256, 2) void step2_kernel(
    const half_t* __restrict__ att_h,
    const half_t* __restrict__ wih2, const half_t* __restrict__ whh2,
    const float* __restrict__ b_ih2, const float* __restrict__ b_hh2,
    const half_t* __restrict__ h2_src, half_t* __restrict__ h2_dst,
    const int* __restrict__ cap_len, int t)
{
    __shared__ half_t lds[3 * (64 * KS + 3 * 64 * KS)];
    floatx4 acc[4][2][2];
#pragma unroll
    for (int g = 0; g < 4; ++g) for (int im = 0; im < 2; ++im) for (int in = 0; in < 2; ++in)
        acc[g][im][in] = (floatx4){0.f, 0.f, 0.f, 0.f};
    int m0, c0; remap512(blockIdx.x, blockIdx.y, 64, m0, c0);
    gemm_ring<3, 64, 3, 4, 0, 1, 2, 0, 1, 3>(
        att_h, CD, wih2, (long)HD * CD, CD / KS,
        h2_src, HD, whh2, (long)HD * HD, HD / KS, m0, c0, lds, acc);

    const int lane = threadIdx.x & 63;
    const int wid = threadIdx.x >> 6;
    const int wr = (wid >> 1) * 32, wc = (wid & 1) * 32;
#pragma unroll
    for (int im = 0; im < 2; ++im)
#pragma unroll
    for (int in = 0; in < 2; ++in) {
        const int mb = m0 + wr + im * 16 + (lane >> 4) * 4;
        const int c  = c0 + wc + in * 16 + (lane & 15);
        const float br = b_ih2[c] + b_hh2[c];
        const float bz = b_ih2[HD + c] + b_hh2[HD + c];
        const float bin_ = b_ih2[2 * HD + c];
        const float bhn  = b_hh2[2 * HD + c];
#pragma unroll
        for (int j = 0; j < 4; ++j) {
            const int m = mb + j;
            const float r = sigmoidf_(acc[0][im][in][j] + br);
            const float z = sigmoidf_(acc[1][im][in][j] + bz);
            const float n = tanhf_(acc[2][im][in][j] + bin_ + r * (acc[3][im][in][j] + bhn));
            const float h_old = (float)h2_src[m * HD + c];
            const bool act = t < cap_len[m];
            h2_dst[m * HD + c] = (half_t)(act ? ((1.f - z) * n + z * h_old) : h_old);
        }
    }
}

extern "C" void kernel_launch(void* const* d_in, const int* in_sizes, int n_in,
                              void* d_out, int out_size, void* d_ws, size_t ws_size,
                              hipStream_t stream)
{
    (void)in_sizes; (void)n_in; (void)out_size; (void)ws_size;
    const float* v     = (const float*)d_in[0];
    const float* q     = (const float*)d_in[1];
    const float* cap   = (const float*)d_in[2];
    const int*   cap_len = (const int*)d_in[3];
    const float* w_ih1 = (const float*)d_in[4];
    const float* w_hh1 = (const float*)d_in[5];
    const float* b_ih1 = (const float*)d_in[6];
    const float* b_hh1 = (const float*)d_in[7];
    const float* w_ih2 = (const float*)d_in[8];
    const float* w_hh2 = (const float*)d_in[9];
    const float* b_ih2 = (const float*)d_in[10];
    const float* b_hh2 = (const float*)d_in[11];
    const float* Wv    = (const float*)d_in[12];
    const float* Wq    = (const float*)d_in[13];
    const float* Wfc   = (const float*)d_in[14];

    float* out_max = (float*)d_out;                    // [NB, HD]
    float* alphas  = (float*)d_out + (size_t)NB * HD;  // [NB, NT, CD]

    half_t* p = (half_t*)d_ws;
    half_t* v_h    = p; p += (size_t)NB * VD;
    half_t* q_h    = p; p += (size_t)NB * QD;
    half_t* cap_h  = p; p += (size_t)NB * NT * CD;
    half_t* wih1_h = p; p += 3 * CD * CD;
    half_t* whh1_h = p; p += 3 * CD * CD;
    half_t* wih2_h = p; p += 3 * HD * CD;
    half_t* whh2_h = p; p += 3 * HD * HD;
    half_t* wfc_h  = p; p += HD * HD;
    half_t* wv_h   = p; p += CD * VD;
    half_t* wq_h   = p; p += CD * QD;
    half_t* h1b[2]; h1b[0] = p; p += (size_t)NB * CD; h1b[1] = p; p += (size_t)NB * CD;
    half_t* h2b[2]; h2b[0] = p; p += (size_t)NB * HD; h2b[1] = p; p += (size_t)NB * HD;
    half_t* att_h  = p; p += (size_t)NB * CD;
    float* fvq = (float*)p;

    hipMemsetAsync(d_out, 0, (size_t)NB * HD * sizeof(float), stream);
    hipMemsetAsync(h1b[0], 0, (size_t)NB * CD * sizeof(half_t), stream);
    hipMemsetAsync(h2b[0], 0, (size_t)NB * HD * sizeof(half_t), stream);

    CvtArgs ca;
    const float* srcs[10] = {v, q, cap, w_ih1, w_hh1, w_ih2, w_hh2, Wfc, Wv, Wq};
    half_t* dsts[10] = {v_h, q_h, cap_h, wih1_h, whh1_h, wih2_h, whh2_h, wfc_h, wv_h, wq_h};
    const int ns[10] = {NB * VD, NB * QD, NB * NT * CD, 3 * CD * CD, 3 * CD * CD,
                        3 * HD * CD, 3 * HD * HD, HD * HD, CD * VD, CD * QD};
    int acc_blk = 0;
    for (int i = 0; i < 10; ++i) {
        ca.src[i] = srcs[i]; ca.dst[i] = dsts[i];
        ca.start[i] = acc_blk; acc_blk += ns[i] / 1024;
    }
    ca.start[10] = acc_blk;
    cvt_all_kernel<<<acc_blk, 256, 0, stream>>>(ca);

    fvq_kernel<<<dim3(16, 32), 256, 0, stream>>>(v_h, wv_h, q_h, wq_h, fvq);

    step1_kernel<<<dim3(16, 32), 256, 0, stream>>>(
        cap_h, wih1_h, whh1_h, b_ih1, b_hh1, h1b[0], h1b[1],
        fvq, cap, cap_len, att_h, alphas, 0);

    for (int t = 0; t < NT; ++t) {
        const int s = t & 1, d = s ^ 1;
        step2_kernel<<<dim3(16, 32), 256, 0, stream>>>(
            att_h, wih2_h, whh2_h, b_ih2, b_hh2, h2b[s], h2b[d], cap_len, t);
        if (t < NT - 1) {
            // step3(t) || step1(t+1) — independent, one kernel, 1024 blocks
            fused31_kernel<<<dim3(16, 64), 256, 0, stream>>>(
                h2b[d], wfc_h, cap_len, out_max, t,
                cap_h, wih1_h, whh1_h, b_ih1, b_hh1, h1b[d], h1b[s],
                fvq, cap, att_h, alphas, t + 1);
        } else {
            step3_kernel<<<dim3(16, 32), 256, 0, stream>>>(
                h2b[d], wfc_h, cap_len, out_max, t);
        }
    }
}

// Round 3
// 1397.855 us; speedup vs baseline: 2.3607x; 2.3607x over previous
//
#include <hip/hip_runtime.h>

typedef _Float16 half_t;
typedef half_t half8 __attribute__((ext_vector_type(8)));
typedef half_t half4 __attribute__((ext_vector_type(4)));
typedef float  floatx4 __attribute__((ext_vector_type(4)));

#define NB 2048
#define NT 20
#define CD 512
#define HD 1024
#define VD 2048
#define QD 1024

// Engine = round-1 proven structure: KS=64, 2-buffer double-buffered loop,
// ONE __syncthreads per K-step (its implicit vmcnt(0) drains stage(s+1),
// which was issued a full compute-phase earlier). BN=32 output cols per
// block -> LDS ring 40KB (3-gate) / 24KB (1-gate) -> 4 blocks/CU, so the
// per-block barrier drain is covered by the other 3 resident blocks (m114).
// LDS linear (global_load_lds dest must be lane-linear, m104); bank swizzle
// applied on the pre-swizzled GLOBAL source chunk (m173): chunk ^= row&7.

__device__ __forceinline__ float sigmoidf_(float x) { return 1.0f / (1.0f + __expf(-x)); }
__device__ __forceinline__ float tanhf_(float x)    { return 1.0f - 2.0f / (1.0f + __expf(2.0f * x)); }
__device__ __forceinline__ float lrelu_(float x)    { return x > 0.0f ? x : 0.01f * x; }

__device__ __forceinline__ void gload16(const half_t* g, half_t* l) {
    __builtin_amdgcn_global_load_lds(
        (const __attribute__((address_space(1))) void*)g,
        (__attribute__((address_space(3))) void*)l, 16, 0, 0);
}

// XCD-aware remap for a flat 1D grid of GX*32 blocks (GX = col-blocks of 32).
// Each XCD owns GX/8 weight-column blocks -> per-XCD weight slice stays
// L2-resident across the whole t-loop; all 32 m-blocks iterate within it.
__device__ __forceinline__ void remap(int flat, int GX, int& m0, int& c0) {
    const int xcd = flat & 7;
    const int i   = flat >> 3;
    c0 = (xcd * (GX >> 3) + (i >> 5)) * 32;
    m0 = (i & 31) * 64;
}

// Dual-phase GEMM: acc[mapA[g]] += A1[64xK1] @ W1_g^T then
// acc[mapB[g]] += A2[64xK2] @ W2_g^T.  W tiles are BN x K, A is 64 x K.
template <int NG, int BN, int NACC,
          int I0A, int I1A, int I2A, int I0B, int I1B, int I2B>
__device__ __forceinline__ void gemm2(
    const half_t* __restrict__ A1, int lda1, const half_t* __restrict__ W1, long gs1, int S1,
    const half_t* __restrict__ A2, int lda2, const half_t* __restrict__ W2, long gs2, int S2,
    int m0, int c0, half_t* lds, floatx4 (&acc)[NACC][2][BN / 32])
{
    constexpr int ASZ = 64 * 64;             // A tile halves
    constexpr int WL  = (NG * BN * 8) / 256; // per-thread W chunk loads
    constexpr int BUF = ASZ + NG * BN * 64;  // halves per buffer
    constexpr int NIN = BN / 32;
    constexpr int map_[3] = {I0A, I1A, I2A};
    constexpr int mapB[3] = {I0B, I1B, I2B};

    const int tid  = threadIdx.x;
    const int lane = tid & 63;
    const int wid  = tid >> 6;
    const int wr   = (wid >> 1) * 32;
    const int wc   = (wid & 1) * (BN / 2);
    const int frow = lane & 15;
    const int cb   = lane >> 4;

    // staging maps: dest lane-linear, source chunk pre-swizzled (^ row&7)
    const int srow = tid >> 3;                    // 0..31
    const int sq   = ((tid & 7) ^ (srow & 7)) * 8;
    const int sdl  = srow * 64 + (tid & 7) * 8;
    const long aoff1 = (long)(m0 + srow) * lda1 + sq;
    const long aoff2 = (long)(m0 + srow) * lda2 + sq;

    int  wdst[WL];
    long woff1[WL], woff2[WL];
#pragma unroll
    for (int j = 0; j < WL; ++j) {
        const int u   = tid + j * 256;
        const int g   = u / (BN * 8);
        const int idx = u - g * (BN * 8);
        const int row = idx >> 3;
        const int q   = ((idx & 7) ^ (row & 7)) * 8;
        wdst[j]  = ASZ + u * 8;
        woff1[j] = (long)g * gs1 + (long)(c0 + row) * (S1 * 64) + q;
        woff2[j] = (long)g * gs2 + (long)(c0 + row) * (S2 * 64) + q;
    }

    const int S = S1 + S2;
    auto stage = [&](int s, int buf) {
        half_t* lb = lds + buf * BUF;
        if (s < S1) {
            const int k0 = s * 64;
            gload16(A1 + aoff1 + k0,             lb + sdl);
            gload16(A1 + aoff1 + 32 * lda1 + k0, lb + 32 * 64 + sdl);
#pragma unroll
            for (int j = 0; j < WL; ++j) gload16(W1 + woff1[j] + k0, lb + wdst[j]);
        } else {
            const int k0 = (s - S1) * 64;
            gload16(A2 + aoff2 + k0,             lb + sdl);
            gload16(A2 + aoff2 + 32 * lda2 + k0, lb + 32 * 64 + sdl);
#pragma unroll
            for (int j = 0; j < WL; ++j) gload16(W2 + woff2[j] + k0, lb + wdst[j]);
        }
    };

    stage(0, 0);
    __syncthreads();
    int cur = 0;
    for (int s = 0; s < S; ++s) {
        if (s + 1 < S) stage(s + 1, cur ^ 1);
        const half_t* lb = lds + cur * BUF;
        const bool pa = (s < S1);
#pragma unroll
        for (int kk = 0; kk < 2; ++kk) {
            half8 af[2];
#pragma unroll
            for (int im = 0; im < 2; ++im) {
                const int r = wr + im * 16 + frow;
                af[im] = *(const half8*)(lb + r * 64 + (((kk * 4 + cb) ^ (r & 7)) * 8));
            }
#pragma unroll
            for (int g = 0; g < NG; ++g) {
#pragma unroll
                for (int in = 0; in < NIN; ++in) {
                    const int r = wc + in * 16 + frow;
                    const half8 bf = *(const half8*)(lb + ASZ + g * (BN * 64) + r * 64 +
                                                     (((kk * 4 + cb) ^ (r & 7)) * 8));
                    const int d = pa ? map_[g] : mapB[g];
#pragma unroll
                    for (int im = 0; im < 2; ++im)
                        acc[d][im][in] = __builtin_amdgcn_mfma_f32_16x16x32_f16(
                            af[im], bf, acc[d][im][in], 0, 0, 0);
                }
            }
        }
        __syncthreads();
        cur ^= 1;
    }
}

// ---- fused fp32->fp16 conversion of all 10 buffers in one launch ----
struct CvtArgs {
    const float* src[10];
    half_t* dst[10];
    int start[11];
};
__global__ void cvt_all_kernel(CvtArgs a) {
    const int b = blockIdx.x;
    int i = 0;
#pragma unroll
    for (int k = 0; k < 9; ++k) i += (b >= a.start[k + 1]);
    const int idx = ((b - a.start[i]) * 256 + (int)threadIdx.x) * 4;
    float4 f = *(const float4*)(a.src[i] + idx);
    half4 h = {(half_t)f.x, (half_t)f.y, (half_t)f.z, (half_t)f.w};
    *(half4*)(a.dst[i] + idx) = h;
}

// fvq = leaky(v@Wv^T) + leaky(q@Wq^T)   [NB, CD] fp32.  BN=32, 512 blocks.
__global__ __launch_bounds__(256, 4) void fvq_kernel(
    const half_t* __restrict__ v_h, const half_t* __restrict__ wv_w,
    const half_t* __restrict__ q_h, const half_t* __restrict__ wq_w,
    float* __restrict__ fvq)
{
    __shared__ half_t lds[2 * (64 * 64 + 32 * 64)];
    floatx4 acc[2][2][1];
#pragma unroll
    for (int g = 0; g < 2; ++g) for (int im = 0; im < 2; ++im)
        acc[g][im][0] = (floatx4){0.f, 0.f, 0.f, 0.f};
    int m0, c0; remap(blockIdx.x, 16, m0, c0);
    gemm2<1, 32, 2, 0, 0, 0, 1, 0, 0>(
        v_h, VD, wv_w, 0, VD / 64, q_h, QD, wq_w, 0, QD / 64, m0, c0, lds, acc);

    const int lane = threadIdx.x & 63;
    const int wid = threadIdx.x >> 6;
    const int wr = (wid >> 1) * 32, wc = (wid & 1) * 16;
#pragma unroll
    for (int im = 0; im < 2; ++im) {
        const int mb = m0 + wr + im * 16 + (lane >> 4) * 4;
        const int c  = c0 + wc + (lane & 15);
#pragma unroll
        for (int j = 0; j < 4; ++j)
            fvq[(mb + j) * CD + c] = lrelu_(acc[0][im][0][j]) + lrelu_(acc[1][im][0][j]);
    }
}

// step1 body: h1' = GRUCell(x_t, h1); att = sigmoid(h1'*fvq)*x_t; alphas.
// acc: 0 = i_r+h_r, 1 = i_z+h_z, 2 = i_n, 3 = h_n.  BN=32, 512-block role.
__device__ __forceinline__ void step1_body(
    int flat,
    const half_t* __restrict__ cap_h,
    const half_t* __restrict__ wih1, const half_t* __restrict__ whh1,
    const float* __restrict__ b_ih1, const float* __restrict__ b_hh1,
    const half_t* __restrict__ h1_src, half_t* __restrict__ h1_dst,
    const float* __restrict__ fvq, const float* __restrict__ caption,
    const int* __restrict__ cap_len,
    half_t* __restrict__ att_h, float* __restrict__ alphas, int t, half_t* lds)
{
    floatx4 acc[4][2][1];
#pragma unroll
    for (int g = 0; g < 4; ++g) for (int im = 0; im < 2; ++im)
        acc[g][im][0] = (floatx4){0.f, 0.f, 0.f, 0.f};
    int m0, c0; remap(flat, 16, m0, c0);
    gemm2<3, 32, 4, 0, 1, 2, 0, 1, 3>(
        cap_h + t * CD, NT * CD, wih1, (long)CD * CD, CD / 64,
        h1_src, CD, whh1, (long)CD * CD, CD / 64, m0, c0, lds, acc);

    const int lane = threadIdx.x & 63;
    const int wid = threadIdx.x >> 6;
    const int wr = (wid >> 1) * 32, wc = (wid & 1) * 16;
#pragma unroll
    for (int im = 0; im < 2; ++im) {
        const int mb = m0 + wr + im * 16 + (lane >> 4) * 4;
        const int c  = c0 + wc + (lane & 15);
        const float br = b_ih1[c] + b_hh1[c];
        const float bz = b_ih1[CD + c] + b_hh1[CD + c];
        const float bin_ = b_ih1[2 * CD + c];
        const float bhn  = b_hh1[2 * CD + c];
#pragma unroll
        for (int j = 0; j < 4; ++j) {
            const int m = mb + j;
            const float r = sigmoidf_(acc[0][im][0][j] + br);
            const float z = sigmoidf_(acc[1][im][0][j] + bz);
            const float n = tanhf_(acc[2][im][0][j] + bin_ + r * (acc[3][im][0][j] + bhn));
            const float h_old = (float)h1_src[m * CD + c];
            const bool act = t < cap_len[m];
            const float h_new = act ? ((1.f - z) * n + z * h_old) : h_old;
            const float x = caption[(m * NT + t) * CD + c];
            const float at = sigmoidf_(h_new * fvq[m * CD + c]) * x;
            h1_dst[m * CD + c] = (half_t)h_new;
            att_h[m * CD + c]  = (half_t)at;
            alphas[(m * NT + t) * CD + c] = act ? at : 0.f;
        }
    }
}

// step3 body: out = max(out, active ? leaky(h2 @ Wfc^T) : skip). BN=32, 1024-block role.
__device__ __forceinline__ void step3_body(
    int flat,
    const half_t* __restrict__ h2_cur, const half_t* __restrict__ wfc,
    const int* __restrict__ cap_len, float* __restrict__ outmax, int t, half_t* lds)
{
    floatx4 acc[1][2][1];
#pragma unroll
    for (int im = 0; im < 2; ++im)
        acc[0][im][0] = (floatx4){0.f, 0.f, 0.f, 0.f};
    int m0, c0; remap(flat, 32, m0, c0);
    gemm2<1, 32, 1, 0, 0, 0, 0, 0, 0>(
        h2_cur, HD, wfc, 0, HD / 64,
        h2_cur, HD, wfc, 0, 0, m0, c0, lds, acc);

    const int lane = threadIdx.x & 63;
    const int wid = threadIdx.x >> 6;
    const int wr = (wid >> 1) * 32, wc = (wid & 1) * 16;
#pragma unroll
    for (int im = 0; im < 2; ++im) {
        const int mb = m0 + wr + im * 16 + (lane >> 4) * 4;
        const int c  = c0 + wc + (lane & 15);
#pragma unroll
        for (int j = 0; j < 4; ++j) {
            const int m = mb + j;
            if (t < cap_len[m]) {
                const float v0 = lrelu_(acc[0][im][0][j]);
                float* p = &outmax[m * HD + c];
                *p = fmaxf(*p, v0);
            }
        }
    }
}

__global__ __launch_bounds__(256, 4) void step1_kernel(
    const half_t* cap_h, const half_t* wih1, const half_t* whh1,
    const float* b_ih1, const float* b_hh1,
    const half_t* h1_src, half_t* h1_dst, const float* fvq,
    const float* caption, const int* cap_len,
    half_t* att_h, float* alphas, int t)
{
    __shared__ half_t lds[2 * (64 * 64 + 3 * 32 * 64)];
    step1_body(blockIdx.x, cap_h, wih1, whh1, b_ih1, b_hh1,
               h1_src, h1_dst, fvq, caption, cap_len, att_h, alphas, t, lds);
}

__global__ __launch_bounds__(256, 4) void step3_kernel(
    const half_t* h2_cur, const half_t* wfc, const int* cap_len,
    float* outmax, int t)
{
    __shared__ half_t lds[2 * (64 * 64 + 32 * 64)];
    step3_body(blockIdx.x, h2_cur, wfc, cap_len, outmax, t, lds);
}

// fused: step3(t3) on blocks [0,1024), step1(t3+1) on blocks [1024,1536).
// Independent work; one launch fills the machine at 4 blocks/CU.
__global__ __launch_bounds__(256, 4) void fused31_kernel(
    const half_t* h2_cur, const half_t* wfc, const int* cap_len,
    float* outmax, int t3,
    const half_t* cap_h, const half_t* wih1, const half_t* whh1,
    const float* b_ih1, const float* b_hh1,
    const half_t* h1_src, half_t* h1_dst, const float* fvq,
    const float* caption, half_t* att_h, float* alphas, int t1)
{
    __shared__ half_t lds[2 * (64 * 64 + 3 * 32 * 64)];   // 40 KB (step1 shape)
    if (blockIdx.x < 1024)
        step3_body(blockIdx.x, h2_cur, wfc, cap_len, outmax, t3, lds);
    else
        step1_body(blockIdx.x - 1024, cap_h, wih1, whh1, b_ih1, b_hh1,
                   h1_src, h1_dst, fvq, caption, cap_len, att_h, alphas, t1, lds);
}

// step 2: h2' = GRUCell(att, h2).  BN=32, 1024 blocks, 40 KB ring.
__global__ __launch_bounds__(256, 4) void step2_kernel(
    const half_t* __restrict__ att_h,
    const half_t* __restrict__ wih2, const half_t* __restrict__ whh2,
    const float* __restrict__ b_ih2, const float* __restrict__ b_hh2,
    const half_t* __restrict__ h2_src, half_t* __restrict__ h2_dst,
    const int* __restrict__ cap_len, int t)
{
    __shared__ half_t lds[2 * (64 * 64 + 3 * 32 * 64)];
    floatx4 acc[4][2][1];
#pragma unroll
    for (int g = 0; g < 4; ++g) for (int im = 0; im < 2; ++im)
        acc[g][im][0] = (floatx4){0.f, 0.f, 0.f, 0.f};
    int m0, c0; remap(blockIdx.x, 32, m0, c0);
    gemm2<3, 32, 4, 0, 1, 2, 0, 1, 3>(
        att_h, CD, wih2, (long)HD * CD, CD / 64,
        h2_src, HD, whh2, (long)HD * HD, HD / 64, m0, c0, lds, acc);

    const int lane = threadIdx.x & 63;
    const int wid = threadIdx.x >> 6;
    const int wr = (wid >> 1) * 32, wc = (wid & 1) * 16;
#pragma unroll
    for (int im = 0; im < 2; ++im) {
        const int mb = m0 + wr + im * 16 + (lane >> 4) * 4;
        const int c  = c0 + wc + (lane & 15);
        const float br = b_ih2[c] + b_hh2[c];
        const float bz = b_ih2[HD + c] + b_hh2[HD + c];
        const float bin_ = b_ih2[2 * HD + c];
        const float bhn  = b_hh2[2 * HD + c];
#pragma unroll
        for (int j = 0; j < 4; ++j) {
            const int m = mb + j;
            const float r = sigmoidf_(acc[0][im][0][j] + br);
            const float z = sigmoidf_(acc[1][im][0][j] + bz);
            const float n = tanhf_(acc[2][im][0][j] + bin_ + r * (acc[3][im][0][j] + bhn));
            const float h_old = (float)h2_src[m * HD + c];
            const bool act = t < cap_len[m];
            h2_dst[m * HD + c] = (half_t)(act ? ((1.f - z) * n + z * h_old) : h_old);
        }
    }
}

extern "C" void kernel_launch(void* const* d_in, const int* in_sizes, int n_in,
                              void* d_out, int out_size, void* d_ws, size_t ws_size,
                              hipStream_t stream)
{
    (void)in_sizes; (void)n_in; (void)out_size; (void)ws_size;
    const float* v     = (const float*)d_in[0];
    const float* q     = (const float*)d_in[1];
    const float* cap   = (const float*)d_in[2];
    const int*   cap_len = (const int*)d_in[3];
    const float* w_ih1 = (const float*)d_in[4];
    const float* w_hh1 = (const float*)d_in[5];
    const float* b_ih1 = (const float*)d_in[6];
    const float* b_hh1 = (const float*)d_in[7];
    const float* w_ih2 = (const float*)d_in[8];
    const float* w_hh2 = (const float*)d_in[9];
    const float* b_ih2 = (const float*)d_in[10];
    const float* b_hh2 = (const float*)d_in[11];
    const float* Wv    = (const float*)d_in[12];
    const float* Wq    = (const float*)d_in[13];
    const float* Wfc   = (const float*)d_in[14];

    float* out_max = (float*)d_out;                    // [NB, HD]
    float* alphas  = (float*)d_out + (size_t)NB * HD;  // [NB, NT, CD]

    half_t* p = (half_t*)d_ws;
    half_t* v_h    = p; p += (size_t)NB * VD;
    half_t* q_h    = p; p += (size_t)NB * QD;
    half_t* cap_h  = p; p += (size_t)NB * NT * CD;
    half_t* wih1_h = p; p += 3 * CD * CD;
    half_t* whh1_h = p; p += 3 * CD * CD;
    half_t* wih2_h = p; p += 3 * HD * CD;
    half_t* whh2_h = p; p += 3 * HD * HD;
    half_t* wfc_h  = p; p += HD * HD;
    half_t* wv_h   = p; p += CD * VD;
    half_t* wq_h   = p; p += CD * QD;
    half_t* h1b[2]; h1b[0] = p; p += (size_t)NB * CD; h1b[1] = p; p += (size_t)NB * CD;
    half_t* h2b[2]; h2b[0] = p; p += (size_t)NB * HD; h2b[1] = p; p += (size_t)NB * HD;
    half_t* att_h  = p; p += (size_t)NB * CD;
    float* fvq = (float*)p;

    hipMemsetAsync(d_out, 0, (size_t)NB * HD * sizeof(float), stream);
    hipMemsetAsync(h1b[0], 0, (size_t)NB * CD * sizeof(half_t), stream);
    hipMemsetAsync(h2b[0], 0, (size_t)NB * HD * sizeof(half_t), stream);

    CvtArgs ca;
    const float* srcs[10] = {v, q, cap, w_ih1, w_hh1, w_ih2, w_hh2, Wfc, Wv, Wq};
    half_t* dsts[10] = {v_h, q_h, cap_h, wih1_h, whh1_h, wih2_h, whh2_h, wfc_h, wv_h, wq_h};
    const int ns[10] = {NB * VD, NB * QD, NB * NT * CD, 3 * CD * CD, 3 * CD * CD,
                        3 * HD * CD, 3 * HD * HD, HD * HD, CD * VD, CD * QD};
    int acc_blk = 0;
    for (int i = 0; i < 10; ++i) {
        ca.src[i] = srcs[i]; ca.dst[i] = dsts[i];
        ca.start[i] = acc_blk; acc_blk += ns[i] / 1024;
    }
    ca.start[10] = acc_blk;
    cvt_all_kernel<<<acc_blk, 256, 0, stream>>>(ca);

    fvq_kernel<<<512, 256, 0, stream>>>(v_h, wv_h, q_h, wq_h, fvq);

    step1_kernel<<<512, 256, 0, stream>>>(
        cap_h, wih1_h, whh1_h, b_ih1, b_hh1, h1b[0], h1b[1],
        fvq, cap, cap_len, att_h, alphas, 0);

    for (int t = 0; t < NT; ++t) {
        const int s = t & 1, d = s ^ 1;
        step2_kernel<<<1024, 256, 0, stream>>>(
            att_h, wih2_h, whh2_h, b_ih2, b_hh2, h2b[s], h2b[d], cap_len, t);
        if (t < NT - 1) {
            fused31_kernel<<<1536, 256, 0, stream>>>(
                h2b[d], wfc_h, cap_len, out_max, t,
                cap_h, wih1_h, whh1_h, b_ih1, b_hh1, h1b[d], h1b[s],
                fvq, cap, att_h, alphas, t + 1);
        } else {
            step3_kernel<<<1024, 256, 0, stream>>>(
                h2b[d], wfc_h, cap_len, out_max, t);
        }
    }
}

// Round 4
// 1297.039 us; speedup vs baseline: 2.5442x; 1.0777x over previous
//
#include <hip/hip_runtime.h>

typedef _Float16 half_t;
typedef half_t half8 __attribute__((ext_vector_type(8)));
typedef half_t half4 __attribute__((ext_vector_type(4)));
typedef float  floatx4 __attribute__((ext_vector_type(4)));

#define NB 2048
#define NT 20
#define CD 512
#define HD 1024
#define VD 2048
#define QD 1024

// Engine (proven, rounds 1/3): KS=64, 2-buffer double-buffer, ONE
// __syncthreads per K-step (implicit vmcnt(0) drains the stage issued a full
// compute-phase earlier). BN=32 -> LDS 40KB (3-gate)/24KB (1-gate) -> 4
// blocks/CU. LDS linear (global_load_lds dest lane-linear, m104); bank
// swizzle on the pre-swizzled GLOBAL source chunk (m173): chunk ^= row&7.
// Round-4 change: launch topology only. step2(t) || step1(t+1) || step3(t-1)
// are mutually independent -> one 2560-block launch per t. fvq folded into
// step1_0 (h1==0 at t=0 kills the gh GEMM).

__device__ __forceinline__ float sigmoidf_(float x) { return 1.0f / (1.0f + __expf(-x)); }
__device__ __forceinline__ float tanhf_(float x)    { return 1.0f - 2.0f / (1.0f + __expf(2.0f * x)); }
__device__ __forceinline__ float lrelu_(float x)    { return x > 0.0f ? x : 0.01f * x; }

__device__ __forceinline__ void gload16(const half_t* g, half_t* l) {
    __builtin_amdgcn_global_load_lds(
        (const __attribute__((address_space(1))) void*)g,
        (__attribute__((address_space(3))) void*)l, 16, 0, 0);
}

// XCD-aware remap for a flat role-grid of GX*32 blocks (GX = col-blocks of 32).
__device__ __forceinline__ void remap(int flat, int GX, int& m0, int& c0) {
    const int xcd = flat & 7;
    const int i   = flat >> 3;
    c0 = (xcd * (GX >> 3) + (i >> 5)) * 32;
    m0 = (i & 31) * 64;
}

// Dual-phase GEMM: acc[mapA[g]] += A1[64xK1] @ W1_g^T then
// acc[mapB[g]] += A2[64xK2] @ W2_g^T.  W tiles are BN x K, A is 64 x K.
template <int NG, int BN, int NACC,
          int I0A, int I1A, int I2A, int I0B, int I1B, int I2B>
__device__ __forceinline__ void gemm2(
    const half_t* __restrict__ A1, int lda1, const half_t* __restrict__ W1, long gs1, int S1,
    const half_t* __restrict__ A2, int lda2, const half_t* __restrict__ W2, long gs2, int S2,
    int m0, int c0, half_t* lds, floatx4 (&acc)[NACC][2][BN / 32])
{
    constexpr int ASZ = 64 * 64;
    constexpr int WL  = (NG * BN * 8) / 256;
    constexpr int BUF = ASZ + NG * BN * 64;
    constexpr int NIN = BN / 32;
    constexpr int map_[3] = {I0A, I1A, I2A};
    constexpr int mapB[3] = {I0B, I1B, I2B};

    const int tid  = threadIdx.x;
    const int lane = tid & 63;
    const int wid  = tid >> 6;
    const int wr   = (wid >> 1) * 32;
    const int wc   = (wid & 1) * (BN / 2);
    const int frow = lane & 15;
    const int cb   = lane >> 4;

    const int srow = tid >> 3;
    const int sq   = ((tid & 7) ^ (srow & 7)) * 8;
    const int sdl  = srow * 64 + (tid & 7) * 8;
    const long aoff1 = (long)(m0 + srow) * lda1 + sq;
    const long aoff2 = (long)(m0 + srow) * lda2 + sq;

    int  wdst[WL];
    long woff1[WL], woff2[WL];
#pragma unroll
    for (int j = 0; j < WL; ++j) {
        const int u   = tid + j * 256;
        const int g   = u / (BN * 8);
        const int idx = u - g * (BN * 8);
        const int row = idx >> 3;
        const int q   = ((idx & 7) ^ (row & 7)) * 8;
        wdst[j]  = ASZ + u * 8;
        woff1[j] = (long)g * gs1 + (long)(c0 + row) * (S1 * 64) + q;
        woff2[j] = (long)g * gs2 + (long)(c0 + row) * (S2 * 64) + q;
    }

    const int S = S1 + S2;
    auto stage = [&](int s, int buf) {
        half_t* lb = lds + buf * BUF;
        if (s < S1) {
            const int k0 = s * 64;
            gload16(A1 + aoff1 + k0,             lb + sdl);
            gload16(A1 + aoff1 + 32 * lda1 + k0, lb + 32 * 64 + sdl);
#pragma unroll
            for (int j = 0; j < WL; ++j) gload16(W1 + woff1[j] + k0, lb + wdst[j]);
        } else {
            const int k0 = (s - S1) * 64;
            gload16(A2 + aoff2 + k0,             lb + sdl);
            gload16(A2 + aoff2 + 32 * lda2 + k0, lb + 32 * 64 + sdl);
#pragma unroll
            for (int j = 0; j < WL; ++j) gload16(W2 + woff2[j] + k0, lb + wdst[j]);
        }
    };

    stage(0, 0);
    __syncthreads();
    int cur = 0;
    for (int s = 0; s < S; ++s) {
        if (s + 1 < S) stage(s + 1, cur ^ 1);
        const half_t* lb = lds + cur * BUF;
        const bool pa = (s < S1);
#pragma unroll
        for (int kk = 0; kk < 2; ++kk) {
            half8 af[2];
#pragma unroll
            for (int im = 0; im < 2; ++im) {
                const int r = wr + im * 16 + frow;
                af[im] = *(const half8*)(lb + r * 64 + (((kk * 4 + cb) ^ (r & 7)) * 8));
            }
#pragma unroll
            for (int g = 0; g < NG; ++g) {
#pragma unroll
                for (int in = 0; in < NIN; ++in) {
                    const int r = wc + in * 16 + frow;
                    const half8 bf = *(const half8*)(lb + ASZ + g * (BN * 64) + r * 64 +
                                                     (((kk * 4 + cb) ^ (r & 7)) * 8));
                    const int d = pa ? map_[g] : mapB[g];
#pragma unroll
                    for (int im = 0; im < 2; ++im)
                        acc[d][im][in] = __builtin_amdgcn_mfma_f32_16x16x32_f16(
                            af[im], bf, acc[d][im][in], 0, 0, 0);
                }
            }
        }
        __syncthreads();
        cur ^= 1;
    }
}

// ---- fused fp32->fp16 conversion of all 10 buffers in one launch ----
struct CvtArgs {
    const float* src[10];
    half_t* dst[10];
    int start[11];
};
__global__ void cvt_all_kernel(CvtArgs a) {
    const int b = blockIdx.x;
    int i = 0;
#pragma unroll
    for (int k = 0; k < 9; ++k) i += (b >= a.start[k + 1]);
    const int idx = ((b - a.start[i]) * 256 + (int)threadIdx.x) * 4;
    float4 f = *(const float4*)(a.src[i] + idx);
    half4 h = {(half_t)f.x, (half_t)f.y, (half_t)f.z, (half_t)f.w};
    *(half4*)(a.dst[i] + idx) = h;
}

// ---- role bodies (round-3 proven) ----

// step1(t>=1): h1' = GRUCell(x_t, h1); att = sigmoid(h1'*fvq)*x_t; alphas.
__device__ __forceinline__ void step1_body(
    int flat,
    const half_t* __restrict__ cap_h,
    const half_t* __restrict__ wih1, const half_t* __restrict__ whh1,
    const float* __restrict__ b_ih1, const float* __restrict__ b_hh1,
    const half_t* __restrict__ h1_src, half_t* __restrict__ h1_dst,
    const float* __restrict__ fvq, const float* __restrict__ caption,
    const int* __restrict__ cap_len,
    half_t* __restrict__ att_w, float* __restrict__ alphas, int t, half_t* lds)
{
    floatx4 acc[4][2][1];
#pragma unroll
    for (int g = 0; g < 4; ++g) for (int im = 0; im < 2; ++im)
        acc[g][im][0] = (floatx4){0.f, 0.f, 0.f, 0.f};
    int m0, c0; remap(flat, 16, m0, c0);
    gemm2<3, 32, 4, 0, 1, 2, 0, 1, 3>(
        cap_h + t * CD, NT * CD, wih1, (long)CD * CD, CD / 64,
        h1_src, CD, whh1, (long)CD * CD, CD / 64, m0, c0, lds, acc);

    const int lane = threadIdx.x & 63;
    const int wid = threadIdx.x >> 6;
    const int wr = (wid >> 1) * 32, wc = (wid & 1) * 16;
#pragma unroll
    for (int im = 0; im < 2; ++im) {
        const int mb = m0 + wr + im * 16 + (lane >> 4) * 4;
        const int c  = c0 + wc + (lane & 15);
        const float br = b_ih1[c] + b_hh1[c];
        const float bz = b_ih1[CD + c] + b_hh1[CD + c];
        const float bin_ = b_ih1[2 * CD + c];
        const float bhn  = b_hh1[2 * CD + c];
#pragma unroll
        for (int j = 0; j < 4; ++j) {
            const int m = mb + j;
            const float r = sigmoidf_(acc[0][im][0][j] + br);
            const float z = sigmoidf_(acc[1][im][0][j] + bz);
            const float n = tanhf_(acc[2][im][0][j] + bin_ + r * (acc[3][im][0][j] + bhn));
            const float h_old = (float)h1_src[m * CD + c];
            const bool act = t < cap_len[m];
            const float h_new = act ? ((1.f - z) * n + z * h_old) : h_old;
            const float x = caption[(m * NT + t) * CD + c];
            const float at = sigmoidf_(h_new * fvq[m * CD + c]) * x;
            h1_dst[m * CD + c] = (half_t)h_new;
            att_w[m * CD + c]  = (half_t)at;
            alphas[(m * NT + t) * CD + c] = act ? at : 0.f;
        }
    }
}

// step2(t): h2' = GRUCell(att, h2)
__device__ __forceinline__ void step2_body(
    int flat,
    const half_t* __restrict__ att_r,
    const half_t* __restrict__ wih2, const half_t* __restrict__ whh2,
    const float* __restrict__ b_ih2, const float* __restrict__ b_hh2,
    const half_t* __restrict__ h2_src, half_t* __restrict__ h2_dst,
    const int* __restrict__ cap_len, int t, half_t* lds)
{
    floatx4 acc[4][2][1];
#pragma unroll
    for (int g = 0; g < 4; ++g) for (int im = 0; im < 2; ++im)
        acc[g][im][0] = (floatx4){0.f, 0.f, 0.f, 0.f};
    int m0, c0; remap(flat, 32, m0, c0);
    gemm2<3, 32, 4, 0, 1, 2, 0, 1, 3>(
        att_r, CD, wih2, (long)HD * CD, CD / 64,
        h2_src, HD, whh2, (long)HD * HD, HD / 64, m0, c0, lds, acc);

    const int lane = threadIdx.x & 63;
    const int wid = threadIdx.x >> 6;
    const int wr = (wid >> 1) * 32, wc = (wid & 1) * 16;
#pragma unroll
    for (int im = 0; im < 2; ++im) {
        const int mb = m0 + wr + im * 16 + (lane >> 4) * 4;
        const int c  = c0 + wc + (lane & 15);
        const float br = b_ih2[c] + b_hh2[c];
        const float bz = b_ih2[HD + c] + b_hh2[HD + c];
        const float bin_ = b_ih2[2 * HD + c];
        const float bhn  = b_hh2[2 * HD + c];
#pragma unroll
        for (int j = 0; j < 4; ++j) {
            const int m = mb + j;
            const float r = sigmoidf_(acc[0][im][0][j] + br);
            const float z = sigmoidf_(acc[1][im][0][j] + bz);
            const float n = tanhf_(acc[2][im][0][j] + bin_ + r * (acc[3][im][0][j] + bhn));
            const float h_old = (float)h2_src[m * HD + c];
            const bool act = t < cap_len[m];
            h2_dst[m * HD + c] = (half_t)(act ? ((1.f - z) * n + z * h_old) : h_old);
        }
    }
}

// step3(t): out = max(out, active ? leaky(h2 @ Wfc^T) : skip)
__device__ __forceinline__ void step3_body(
    int flat,
    const half_t* __restrict__ h2_cur, const half_t* __restrict__ wfc,
    const int* __restrict__ cap_len, float* __restrict__ outmax, int t, half_t* lds)
{
    floatx4 acc[1][2][1];
#pragma unroll
    for (int im = 0; im < 2; ++im)
        acc[0][im][0] = (floatx4){0.f, 0.f, 0.f, 0.f};
    int m0, c0; remap(flat, 32, m0, c0);
    gemm2<1, 32, 1, 0, 0, 0, 0, 0, 0>(
        h2_cur, HD, wfc, 0, HD / 64,
        h2_cur, HD, wfc, 0, 0, m0, c0, lds, acc);

    const int lane = threadIdx.x & 63;
    const int wid = threadIdx.x >> 6;
    const int wr = (wid >> 1) * 32, wc = (wid & 1) * 16;
#pragma unroll
    for (int im = 0; im < 2; ++im) {
        const int mb = m0 + wr + im * 16 + (lane >> 4) * 4;
        const int c  = c0 + wc + (lane & 15);
#pragma unroll
        for (int j = 0; j < 4; ++j) {
            const int m = mb + j;
            if (t < cap_len[m]) {
                const float v0 = lrelu_(acc[0][im][0][j]);
                float* p = &outmax[m * HD + c];
                *p = fmaxf(*p, v0);
            }
        }
    }
}

// ---- step1_0: fvq GEMM + step1(t=0) with h1==0 (gh phase vanishes) ----
__global__ __launch_bounds__(256, 4) void step1_0_kernel(
    const half_t* __restrict__ v_h, const half_t* __restrict__ wv_w,
    const half_t* __restrict__ q_h, const half_t* __restrict__ wq_w,
    const half_t* __restrict__ cap_h, const half_t* __restrict__ wih1,
    const float* __restrict__ b_ih1, const float* __restrict__ b_hh1,
    half_t* __restrict__ h1_dst, float* __restrict__ fvq_out,
    const float* __restrict__ caption, const int* __restrict__ cap_len,
    half_t* __restrict__ att_w, float* __restrict__ alphas)
{
    __shared__ half_t lds[2 * (64 * 64 + 3 * 32 * 64)];
    int m0, c0; remap(blockIdx.x, 16, m0, c0);

    // phase 1: fvq = leaky(v@Wv^T) + leaky(q@Wq^T), per-term acc
    floatx4 acc1[2][2][1];
#pragma unroll
    for (int g = 0; g < 2; ++g) for (int im = 0; im < 2; ++im)
        acc1[g][im][0] = (floatx4){0.f, 0.f, 0.f, 0.f};
    gemm2<1, 32, 2, 0, 0, 0, 1, 0, 0>(
        v_h, VD, wv_w, 0, VD / 64, q_h, QD, wq_w, 0, QD / 64, m0, c0, lds, acc1);

    // phase 2: gi = x_0 @ w_ih1^T only (gh == 0 at t=0)
    floatx4 acc2[3][2][1];
#pragma unroll
    for (int g = 0; g < 3; ++g) for (int im = 0; im < 2; ++im)
        acc2[g][im][0] = (floatx4){0.f, 0.f, 0.f, 0.f};
    gemm2<3, 32, 3, 0, 1, 2, 0, 1, 2>(
        cap_h, NT * CD, wih1, (long)CD * CD, CD / 64,
        cap_h, NT * CD, wih1, (long)CD * CD, 0, m0, c0, lds, acc2);

    const int lane = threadIdx.x & 63;
    const int wid = threadIdx.x >> 6;
    const int wr = (wid >> 1) * 32, wc = (wid & 1) * 16;
#pragma unroll
    for (int im = 0; im < 2; ++im) {
        const int mb = m0 + wr + im * 16 + (lane >> 4) * 4;
        const int c  = c0 + wc + (lane & 15);
        const float br = b_ih1[c] + b_hh1[c];
        const float bz = b_ih1[CD + c] + b_hh1[CD + c];
        const float bin_ = b_ih1[2 * CD + c];
        const float bhn  = b_hh1[2 * CD + c];
#pragma unroll
        for (int j = 0; j < 4; ++j) {
            const int m = mb + j;
            const float fv = lrelu_(acc1[0][im][0][j]) + lrelu_(acc1[1][im][0][j]);
            fvq_out[m * CD + c] = fv;
            const float r = sigmoidf_(acc2[0][im][0][j] + br);
            const float z = sigmoidf_(acc2[1][im][0][j] + bz);
            const float n = tanhf_(acc2[2][im][0][j] + bin_ + r * bhn);
            const bool act = 0 < cap_len[m];
            const float h_new = act ? (1.f - z) * n : 0.f;
            const float x = caption[(m * NT + 0) * CD + c];
            const float at = sigmoidf_(h_new * fv) * x;
            h1_dst[m * CD + c] = (half_t)h_new;
            att_w[m * CD + c]  = (half_t)at;
            alphas[(m * NT + 0) * CD + c] = act ? at : 0.f;
        }
    }
}

// ---- fused321: step2(t) [0,1024) || step1(t+1) [1024,1536) || step3(t-1) [1536,2560) ----
// Launched for t = 0..20; internal guards handle the boundary launches.
__global__ __launch_bounds__(256, 4) void fused321_kernel(
    const half_t* __restrict__ att0, half_t* __restrict__ att1,
    const half_t* __restrict__ wih2, const half_t* __restrict__ whh2,
    const float* __restrict__ b_ih2, const float* __restrict__ b_hh2,
    const half_t* __restrict__ h2b0, half_t* __restrict__ h2b1,
    const half_t* __restrict__ cap_h,
    const half_t* __restrict__ wih1, const half_t* __restrict__ whh1,
    const float* __restrict__ b_ih1, const float* __restrict__ b_hh1,
    const half_t* __restrict__ h1b0, half_t* __restrict__ h1b1,
    const float* __restrict__ fvq, const float* __restrict__ caption,
    const half_t* __restrict__ wfc, const int* __restrict__ cap_len,
    float* __restrict__ outmax, float* __restrict__ alphas, int t)
{
    __shared__ half_t lds[2 * (64 * 64 + 3 * 32 * 64)];
    const int par = t & 1;
    // buffer parity (see host): att[t&1] read by step2(t), att[(t+1)&1] written
    // by step1(t+1); h2b[t&1] read, h2b[(t+1)&1] written; h1b[(t+1)&1] read,
    // h1b[t&1] written.
    const half_t* att_r = par ? att1 : att0;
    half_t*       att_w = par ? (half_t*)att0 : att1;
    const half_t* h2_r  = par ? h2b1 : h2b0;
    half_t*       h2_w  = par ? (half_t*)h2b0 : h2b1;
    const half_t* h1_r  = par ? h1b0 : h1b1;
    half_t*       h1_w  = par ? h1b1 : (half_t*)h1b0;

    const int bx = blockIdx.x;
    if (bx < 1024) {
        if (t < NT)
            step2_body(bx, att_r, wih2, whh2, b_ih2, b_hh2, h2_r, h2_w,
                       cap_len, t, lds);
    } else if (bx < 1536) {
        if (t < NT - 1)
            step1_body(bx - 1024, cap_h, wih1, whh1, b_ih1, b_hh1,
                       h1_r, h1_w, fvq, caption, cap_len, att_w, alphas, t + 1, lds);
    } else {
        if (t >= 1)
            step3_body(bx - 1536, h2_r, wfc, cap_len, outmax, t - 1, lds);
    }
}

extern "C" void kernel_launch(void* const* d_in, const int* in_sizes, int n_in,
                              void* d_out, int out_size, void* d_ws, size_t ws_size,
                              hipStream_t stream)
{
    (void)in_sizes; (void)n_in; (void)out_size; (void)ws_size;
    const float* v     = (const float*)d_in[0];
    const float* q     = (const float*)d_in[1];
    const float* cap   = (const float*)d_in[2];
    const int*   cap_len = (const int*)d_in[3];
    const float* w_ih1 = (const float*)d_in[4];
    const float* w_hh1 = (const float*)d_in[5];
    const float* b_ih1 = (const float*)d_in[6];
    const float* b_hh1 = (const float*)d_in[7];
    const float* w_ih2 = (const float*)d_in[8];
    const float* w_hh2 = (const float*)d_in[9];
    const float* b_ih2 = (const float*)d_in[10];
    const float* b_hh2 = (const float*)d_in[11];
    const float* Wv    = (const float*)d_in[12];
    const float* Wq    = (const float*)d_in[13];
    const float* Wfc   = (const float*)d_in[14];

    float* out_max = (float*)d_out;                    // [NB, HD]
    float* alphas  = (float*)d_out + (size_t)NB * HD;  // [NB, NT, CD]

    half_t* p = (half_t*)d_ws;
    half_t* v_h    = p; p += (size_t)NB * VD;
    half_t* q_h    = p; p += (size_t)NB * QD;
    half_t* cap_h  = p; p += (size_t)NB * NT * CD;
    half_t* wih1_h = p; p += 3 * CD * CD;
    half_t* whh1_h = p; p += 3 * CD * CD;
    half_t* wih2_h = p; p += 3 * HD * CD;
    half_t* whh2_h = p; p += 3 * HD * HD;
    half_t* wfc_h  = p; p += HD * HD;
    half_t* wv_h   = p; p += CD * VD;
    half_t* wq_h   = p; p += CD * QD;
    half_t* h1b0   = p; p += (size_t)NB * CD;
    half_t* h1b1   = p; p += (size_t)NB * CD;
    half_t* h2b0   = p; p += (size_t)NB * HD;
    half_t* h2b1   = p; p += (size_t)NB * HD;
    half_t* att0   = p; p += (size_t)NB * CD;
    half_t* att1   = p; p += (size_t)NB * CD;
    float* fvq = (float*)p;

    // out region must be zeroed (step3 does fmax-RMW); alphas fully written.
    hipMemsetAsync(out_max, 0, (size_t)NB * HD * sizeof(float), stream);
    hipMemsetAsync(h2b0, 0, (size_t)NB * HD * sizeof(half_t), stream);

    CvtArgs ca;
    const float* srcs[10] = {v, q, cap, w_ih1, w_hh1, w_ih2, w_hh2, Wfc, Wv, Wq};
    half_t* dsts[10] = {v_h, q_h, cap_h, wih1_h, whh1_h, wih2_h, whh2_h, wfc_h, wv_h, wq_h};
    const int ns[10] = {NB * VD, NB * QD, NB * NT * CD, 3 * CD * CD, 3 * CD * CD,
                        3 * HD * CD, 3 * HD * HD, HD * HD, CD * VD, CD * QD};
    int acc_blk = 0;
    for (int i = 0; i < 10; ++i) {
        ca.src[i] = srcs[i]; ca.dst[i] = dsts[i];
        ca.start[i] = acc_blk; acc_blk += ns[i] / 1024;
    }
    ca.start[10] = acc_blk;
    cvt_all_kernel<<<acc_blk, 256, 0, stream>>>(ca);

    // t=0: fvq + step1(0) fused (h1==0). Writes h1b1, att0, alphas[:,0,:], fvq.
    step1_0_kernel<<<512, 256, 0, stream>>>(
        v_h, wv_h, q_h, wq_h, cap_h, wih1_h, b_ih1, b_hh1,
        h1b1, fvq, cap, cap_len, att0, alphas);

    // t = 0..20: step2(t) || step1(t+1) || step3(t-1), guards at the edges.
    for (int t = 0; t <= NT; ++t) {
        fused321_kernel<<<2560, 256, 0, stream>>>(
            att0, att1, wih2_h, whh2_h, b_ih2, b_hh2, h2b0, h2b1,
            cap_h, wih1_h, whh1_h, b_ih1, b_hh1, h1b0, h1b1,
            fvq, cap, wfc_h, cap_len, out_max, alphas, t);
    }
}

// Round 5
// 966.224 us; speedup vs baseline: 3.4152x; 1.3424x over previous
//
#include <hip/hip_runtime.h>

typedef _Float16 half_t;
typedef half_t half8 __attribute__((ext_vector_type(8)));
typedef half_t half4 __attribute__((ext_vector_type(4)));
typedef float  floatx4 __attribute__((ext_vector_type(4)));

#define NB 2048
#define NT 20
#define CD 512
#define HD 1024
#define VD 2048
#define QD 1024

// Engine (proven, rounds 1/3/4): KS=64, 2-buffer double-buffer, ONE
// __syncthreads per K-step (implicit vmcnt(0) drains the stage issued a full
// compute-phase earlier). BN=32 -> LDS 40KB (3-gate) -> 4 blocks/CU. LDS is
// linear (global_load_lds dest must be lane-linear, m104); bank swizzle is
// applied on the pre-swizzled GLOBAL source chunk (m173): chunk ^= row&7.
//
// Round-5 change (algorithmic): rows are counting-sorted by cap_len
// descending (perm[], cnt[t] = #rows with cap_len > t). Active test becomes
// row < cnt[t] (scalar), and GEMM blocks with m0 >= cnt[t] exit: expected
// live work = 47.5% of the t-loop. Engine untouched.

__device__ __forceinline__ float sigmoidf_(float x) { return 1.0f / (1.0f + __expf(-x)); }
__device__ __forceinline__ float tanhf_(float x)    { return 1.0f - 2.0f / (1.0f + __expf(2.0f * x)); }
__device__ __forceinline__ float lrelu_(float x)    { return x > 0.0f ? x : 0.01f * x; }

__device__ __forceinline__ void gload16(const half_t* g, half_t* l) {
    __builtin_amdgcn_global_load_lds(
        (const __attribute__((address_space(1))) void*)g,
        (__attribute__((address_space(3))) void*)l, 16, 0, 0);
}

// XCD-aware remap for a flat role-grid of GX*32 blocks (GX = col-blocks of 32).
__device__ __forceinline__ void remap(int flat, int GX, int& m0, int& c0) {
    const int xcd = flat & 7;
    const int i   = flat >> 3;
    c0 = (xcd * (GX >> 3) + (i >> 5)) * 32;
    m0 = (i & 31) * 64;
}

// Dual-phase GEMM: acc[mapA[g]] += A1[64xK1] @ W1_g^T then
// acc[mapB[g]] += A2[64xK2] @ W2_g^T.  W tiles are BN x K, A is 64 x K.
template <int NG, int BN, int NACC,
          int I0A, int I1A, int I2A, int I0B, int I1B, int I2B>
__device__ __forceinline__ void gemm2(
    const half_t* __restrict__ A1, int lda1, const half_t* __restrict__ W1, long gs1, int S1,
    const half_t* __restrict__ A2, int lda2, const half_t* __restrict__ W2, long gs2, int S2,
    int m0, int c0, half_t* lds, floatx4 (&acc)[NACC][2][BN / 32])
{
    constexpr int ASZ = 64 * 64;
    constexpr int WL  = (NG * BN * 8) / 256;
    constexpr int BUF = ASZ + NG * BN * 64;
    constexpr int NIN = BN / 32;
    constexpr int map_[3] = {I0A, I1A, I2A};
    constexpr int mapB[3] = {I0B, I1B, I2B};

    const int tid  = threadIdx.x;
    const int lane = tid & 63;
    const int wid  = tid >> 6;
    const int wr   = (wid >> 1) * 32;
    const int wc   = (wid & 1) * (BN / 2);
    const int frow = lane & 15;
    const int cb   = lane >> 4;

    const int srow = tid >> 3;
    const int sq   = ((tid & 7) ^ (srow & 7)) * 8;
    const int sdl  = srow * 64 + (tid & 7) * 8;
    const long aoff1 = (long)(m0 + srow) * lda1 + sq;
    const long aoff2 = (long)(m0 + srow) * lda2 + sq;

    int  wdst[WL];
    long woff1[WL], woff2[WL];
#pragma unroll
    for (int j = 0; j < WL; ++j) {
        const int u   = tid + j * 256;
        const int g   = u / (BN * 8);
        const int idx = u - g * (BN * 8);
        const int row = idx >> 3;
        const int q   = ((idx & 7) ^ (row & 7)) * 8;
        wdst[j]  = ASZ + u * 8;
        woff1[j] = (long)g * gs1 + (long)(c0 + row) * (S1 * 64) + q;
        woff2[j] = (long)g * gs2 + (long)(c0 + row) * (S2 * 64) + q;
    }

    const int S = S1 + S2;
    auto stage = [&](int s, int buf) {
        half_t* lb = lds + buf * BUF;
        if (s < S1) {
            const int k0 = s * 64;
            gload16(A1 + aoff1 + k0,             lb + sdl);
            gload16(A1 + aoff1 + 32 * lda1 + k0, lb + 32 * 64 + sdl);
#pragma unroll
            for (int j = 0; j < WL; ++j) gload16(W1 + woff1[j] + k0, lb + wdst[j]);
        } else {
            const int k0 = (s - S1) * 64;
            gload16(A2 + aoff2 + k0,             lb + sdl);
            gload16(A2 + aoff2 + 32 * lda2 + k0, lb + 32 * 64 + sdl);
#pragma unroll
            for (int j = 0; j < WL; ++j) gload16(W2 + woff2[j] + k0, lb + wdst[j]);
        }
    };

    stage(0, 0);
    __syncthreads();
    int cur = 0;
    for (int s = 0; s < S; ++s) {
        if (s + 1 < S) stage(s + 1, cur ^ 1);
        const half_t* lb = lds + cur * BUF;
        const bool pa = (s < S1);
#pragma unroll
        for (int kk = 0; kk < 2; ++kk) {
            half8 af[2];
#pragma unroll
            for (int im = 0; im < 2; ++im) {
                const int r = wr + im * 16 + frow;
                af[im] = *(const half8*)(lb + r * 64 + (((kk * 4 + cb) ^ (r & 7)) * 8));
            }
#pragma unroll
            for (int g = 0; g < NG; ++g) {
#pragma unroll
                for (int in = 0; in < NIN; ++in) {
                    const int r = wc + in * 16 + frow;
                    const half8 bf = *(const half8*)(lb + ASZ + g * (BN * 64) + r * 64 +
                                                     (((kk * 4 + cb) ^ (r & 7)) * 8));
                    const int d = pa ? map_[g] : mapB[g];
#pragma unroll
                    for (int im = 0; im < 2; ++im)
                        acc[d][im][in] = __builtin_amdgcn_mfma_f32_16x16x32_f16(
                            af[im], bf, acc[d][im][in], 0, 0, 0);
                }
            }
        }
        __syncthreads();
        cur ^= 1;
    }
}

// ---- counting sort of rows by cap_len DESCENDING ----
// perm[pos] = original row; cnt[t] = #{cap_len > t} (= active rows at step t,
// which after sorting form the prefix [0, cnt[t]) ).
__global__ void sort_kernel(const int* __restrict__ cap_len,
                            int* __restrict__ perm, int* __restrict__ cnt)
{
    __shared__ int hist[NT];
    __shared__ int off[NT];
    const int tid = threadIdx.x;
    if (tid < NT) hist[tid] = 0;
    __syncthreads();
    for (int i = tid; i < NB; i += 256) atomicAdd(&hist[cap_len[i]], 1);
    __syncthreads();
    if (tid == 0) {
        int run = 0;
        for (int v = NT - 1; v >= 0; --v) { off[v] = run; run += hist[v]; }
        for (int t = 0; t < NT; ++t) cnt[t] = off[t];   // off[t] == #{cap_len > t}
        for (int t = NT; t < 32; ++t) cnt[t] = 0;
    }
    __syncthreads();
    for (int i = tid; i < NB; i += 256) {
        const int pos = atomicAdd(&off[cap_len[i]], 1);
        perm[pos] = i;
    }
}

// ---- fused fp32->fp16 conversion; per-row buffers are PERMUTED into sorted
// order and trimmed to rows < cnt[0] (rows never active are never read). ----
struct CvtArgs {
    const float* src[10];
    half_t* dst[10];
    int start[11];
    int rowlen[10];        // 0 = not per-row (weights)
    const int* perm;
    const int* cnt;
};
__global__ void cvt_all_kernel(CvtArgs a) {
    const int b = blockIdx.x;
    int i = 0;
#pragma unroll
    for (int k = 0; k < 9; ++k) i += (b >= a.start[k + 1]);
    const int idx = ((b - a.start[i]) * 256 + (int)threadIdx.x) * 4;
    long sidx = idx;
    const int rl = a.rowlen[i];
    if (rl) {
        const int row = idx / rl;               // uniform per block (rl | 1024*n)
        if (row >= a.cnt[0]) return;
        sidx = (long)a.perm[row] * rl + (idx - row * rl);
    }
    float4 f = *(const float4*)(a.src[i] + sidx);
    half4 h = {(half_t)f.x, (half_t)f.y, (half_t)f.z, (half_t)f.w};
    *(half4*)(a.dst[i] + idx) = h;
}

// ---- role bodies (sorted row space; cn = cnt[t] for this role) ----

// step1(t>=1): h1' = GRUCell(x_t, h1); att = sigmoid(h1'*fvq)*x_t; alphas.
__device__ __forceinline__ void step1_body(
    int flat,
    const half_t* __restrict__ cap_h,
    const half_t* __restrict__ wih1, const half_t* __restrict__ whh1,
    const float* __restrict__ b_ih1, const float* __restrict__ b_hh1,
    const half_t* __restrict__ h1_src, half_t* __restrict__ h1_dst,
    const float* __restrict__ fvq, const float* __restrict__ caption,
    const int* __restrict__ perm, int cn,
    half_t* __restrict__ att_w, float* __restrict__ alphas, int t, half_t* lds)
{
    int m0, c0; remap(flat, 16, m0, c0);
    if (m0 >= cn) return;
    floatx4 acc[4][2][1];
#pragma unroll
    for (int g = 0; g < 4; ++g) for (int im = 0; im < 2; ++im)
        acc[g][im][0] = (floatx4){0.f, 0.f, 0.f, 0.f};
    gemm2<3, 32, 4, 0, 1, 2, 0, 1, 3>(
        cap_h + t * CD, NT * CD, wih1, (long)CD * CD, CD / 64,
        h1_src, CD, whh1, (long)CD * CD, CD / 64, m0, c0, lds, acc);

    const int lane = threadIdx.x & 63;
    const int wid = threadIdx.x >> 6;
    const int wr = (wid >> 1) * 32, wc = (wid & 1) * 16;
#pragma unroll
    for (int im = 0; im < 2; ++im) {
        const int mb = m0 + wr + im * 16 + (lane >> 4) * 4;
        const int c  = c0 + wc + (lane & 15);
        const float br = b_ih1[c] + b_hh1[c];
        const float bz = b_ih1[CD + c] + b_hh1[CD + c];
        const float bin_ = b_ih1[2 * CD + c];
        const float bhn  = b_hh1[2 * CD + c];
#pragma unroll
        for (int j = 0; j < 4; ++j) {
            const int m = mb + j;
            const float r = sigmoidf_(acc[0][im][0][j] + br);
            const float z = sigmoidf_(acc[1][im][0][j] + bz);
            const float n = tanhf_(acc[2][im][0][j] + bin_ + r * (acc[3][im][0][j] + bhn));
            const float h_old = (float)h1_src[m * CD + c];
            const bool act = m < cn;
            const float h_new = act ? ((1.f - z) * n + z * h_old) : h_old;
            const int orig = perm[m];
            const float x = caption[((long)orig * NT + t) * CD + c];
            const float at = sigmoidf_(h_new * fvq[m * CD + c]) * x;
            h1_dst[m * CD + c] = (half_t)h_new;
            att_w[m * CD + c]  = (half_t)at;
            if (act) alphas[((long)orig * NT + t) * CD + c] = at;
        }
    }
}

// step2(t): h2' = GRUCell(att, h2)
__device__ __forceinline__ void step2_body(
    int flat,
    const half_t* __restrict__ att_r,
    const half_t* __restrict__ wih2, const half_t* __restrict__ whh2,
    const float* __restrict__ b_ih2, const float* __restrict__ b_hh2,
    const half_t* __restrict__ h2_src, half_t* __restrict__ h2_dst,
    int cn, int t, half_t* lds)
{
    int m0, c0; remap(flat, 32, m0, c0);
    if (m0 >= cn) return;
    floatx4 acc[4][2][1];
#pragma unroll
    for (int g = 0; g < 4; ++g) for (int im = 0; im < 2; ++im)
        acc[g][im][0] = (floatx4){0.f, 0.f, 0.f, 0.f};
    gemm2<3, 32, 4, 0, 1, 2, 0, 1, 3>(
        att_r, CD, wih2, (long)HD * CD, CD / 64,
        h2_src, HD, whh2, (long)HD * HD, HD / 64, m0, c0, lds, acc);

    const int lane = threadIdx.x & 63;
    const int wid = threadIdx.x >> 6;
    const int wr = (wid >> 1) * 32, wc = (wid & 1) * 16;
#pragma unroll
    for (int im = 0; im < 2; ++im) {
        const int mb = m0 + wr + im * 16 + (lane >> 4) * 4;
        const int c  = c0 + wc + (lane & 15);
        const float br = b_ih2[c] + b_hh2[c];
        const float bz = b_ih2[HD + c] + b_hh2[HD + c];
        const float bin_ = b_ih2[2 * HD + c];
        const float bhn  = b_hh2[2 * HD + c];
#pragma unroll
        for (int j = 0; j < 4; ++j) {
            const int m = mb + j;
            const float r = sigmoidf_(acc[0][im][0][j] + br);
            const float z = sigmoidf_(acc[1][im][0][j] + bz);
            const float n = tanhf_(acc[2][im][0][j] + bin_ + r * (acc[3][im][0][j] + bhn));
            const float h_old = (float)h2_src[m * HD + c];
            const bool act = m < cn;
            h2_dst[m * HD + c] = (half_t)(act ? ((1.f - z) * n + z * h_old) : h_old);
        }
    }
}

// step3(t): out = max(out, active ? leaky(h2 @ Wfc^T) : skip)
__device__ __forceinline__ void step3_body(
    int flat,
    const half_t* __restrict__ h2_cur, const half_t* __restrict__ wfc,
    const int* __restrict__ perm, int cn,
    float* __restrict__ outmax, half_t* lds)
{
    int m0, c0; remap(flat, 32, m0, c0);
    if (m0 >= cn) return;
    floatx4 acc[1][2][1];
#pragma unroll
    for (int im = 0; im < 2; ++im)
        acc[0][im][0] = (floatx4){0.f, 0.f, 0.f, 0.f};
    gemm2<1, 32, 1, 0, 0, 0, 0, 0, 0>(
        h2_cur, HD, wfc, 0, HD / 64,
        h2_cur, HD, wfc, 0, 0, m0, c0, lds, acc);

    const int lane = threadIdx.x & 63;
    const int wid = threadIdx.x >> 6;
    const int wr = (wid >> 1) * 32, wc = (wid & 1) * 16;
#pragma unroll
    for (int im = 0; im < 2; ++im) {
        const int mb = m0 + wr + im * 16 + (lane >> 4) * 4;
        const int c  = c0 + wc + (lane & 15);
#pragma unroll
        for (int j = 0; j < 4; ++j) {
            const int m = mb + j;
            if (m < cn) {
                const int orig = perm[m];
                const float v0 = lrelu_(acc[0][im][0][j]);
                float* p = &outmax[(long)orig * HD + c];
                *p = fmaxf(*p, v0);
            }
        }
    }
}

// ---- step1_0: fvq GEMM + step1(t=0) with h1==0 (gh phase vanishes) ----
__global__ __launch_bounds__(256, 4) void step1_0_kernel(
    const half_t* __restrict__ v_h, const half_t* __restrict__ wv_w,
    const half_t* __restrict__ q_h, const half_t* __restrict__ wq_w,
    const half_t* __restrict__ cap_h, const half_t* __restrict__ wih1,
    const float* __restrict__ b_ih1, const float* __restrict__ b_hh1,
    half_t* __restrict__ h1_dst, float* __restrict__ fvq_out,
    const float* __restrict__ caption, const int* __restrict__ perm,
    const int* __restrict__ cnt,
    half_t* __restrict__ att_w, float* __restrict__ alphas)
{
    __shared__ half_t lds[2 * (64 * 64 + 3 * 32 * 64)];
    const int cn = cnt[0];
    int m0, c0; remap(blockIdx.x, 16, m0, c0);
    if (m0 >= cn) return;

    floatx4 acc1[2][2][1];
#pragma unroll
    for (int g = 0; g < 2; ++g) for (int im = 0; im < 2; ++im)
        acc1[g][im][0] = (floatx4){0.f, 0.f, 0.f, 0.f};
    gemm2<1, 32, 2, 0, 0, 0, 1, 0, 0>(
        v_h, VD, wv_w, 0, VD / 64, q_h, QD, wq_w, 0, QD / 64, m0, c0, lds, acc1);

    floatx4 acc2[3][2][1];
#pragma unroll
    for (int g = 0; g < 3; ++g) for (int im = 0; im < 2; ++im)
        acc2[g][im][0] = (floatx4){0.f, 0.f, 0.f, 0.f};
    gemm2<3, 32, 3, 0, 1, 2, 0, 1, 2>(
        cap_h, NT * CD, wih1, (long)CD * CD, CD / 64,
        cap_h, NT * CD, wih1, (long)CD * CD, 0, m0, c0, lds, acc2);

    const int lane = threadIdx.x & 63;
    const int wid = threadIdx.x >> 6;
    const int wr = (wid >> 1) * 32, wc = (wid & 1) * 16;
#pragma unroll
    for (int im = 0; im < 2; ++im) {
        const int mb = m0 + wr + im * 16 + (lane >> 4) * 4;
        const int c  = c0 + wc + (lane & 15);
        const float br = b_ih1[c] + b_hh1[c];
        const float bz = b_ih1[CD + c] + b_hh1[CD + c];
        const float bin_ = b_ih1[2 * CD + c];
        const float bhn  = b_hh1[2 * CD + c];
#pragma unroll
        for (int j = 0; j < 4; ++j) {
            const int m = mb + j;
            const float fv = lrelu_(acc1[0][im][0][j]) + lrelu_(acc1[1][im][0][j]);
            fvq_out[m * CD + c] = fv;
            const float r = sigmoidf_(acc2[0][im][0][j] + br);
            const float z = sigmoidf_(acc2[1][im][0][j] + bz);
            const float n = tanhf_(acc2[2][im][0][j] + bin_ + r * bhn);
            const bool act = m < cn;
            const float h_new = act ? (1.f - z) * n : 0.f;
            const int orig = perm[m];
            const float x = caption[(long)orig * NT * CD + c];
            const float at = sigmoidf_(h_new * fv) * x;
            h1_dst[m * CD + c] = (half_t)h_new;
            att_w[m * CD + c]  = (half_t)at;
            if (act) alphas[(long)orig * NT * CD + c] = at;
        }
    }
}

// ---- fused321: step2(t) [0,1024) || step1(t+1) [1024,1536) || step3(t-1) [1536,2560) ----
__global__ __launch_bounds__(256, 4) void fused321_kernel(
    const half_t* __restrict__ att0, half_t* __restrict__ att1,
    const half_t* __restrict__ wih2, const half_t* __restrict__ whh2,
    const float* __restrict__ b_ih2, const float* __restrict__ b_hh2,
    const half_t* __restrict__ h2b0, half_t* __restrict__ h2b1,
    const half_t* __restrict__ cap_h,
    const half_t* __restrict__ wih1, const half_t* __restrict__ whh1,
    const float* __restrict__ b_ih1, const float* __restrict__ b_hh1,
    const half_t* __restrict__ h1b0, half_t* __restrict__ h1b1,
    const float* __restrict__ fvq, const float* __restrict__ caption,
    const half_t* __restrict__ wfc,
    const int* __restrict__ perm, const int* __restrict__ cnt,
    float* __restrict__ outmax, float* __restrict__ alphas, int t)
{
    __shared__ half_t lds[2 * (64 * 64 + 3 * 32 * 64)];
    const int par = t & 1;
    const half_t* att_r = par ? att1 : att0;
    half_t*       att_w = par ? (half_t*)att0 : att1;
    const half_t* h2_r  = par ? h2b1 : h2b0;
    half_t*       h2_w  = par ? (half_t*)h2b0 : h2b1;
    const half_t* h1_r  = par ? h1b0 : h1b1;
    half_t*       h1_w  = par ? h1b1 : (half_t*)h1b0;

    const int bx = blockIdx.x;
    if (bx < 1024) {
        if (t < NT)
            step2_body(bx, att_r, wih2, whh2, b_ih2, b_hh2, h2_r, h2_w,
                       cnt[t], t, lds);
    } else if (bx < 1536) {
        if (t < NT - 1)
            step1_body(bx - 1024, cap_h, wih1, whh1, b_ih1, b_hh1,
                       h1_r, h1_w, fvq, caption, perm, cnt[t + 1],
                       att_w, alphas, t + 1, lds);
    } else {
        if (t >= 1)
            step3_body(bx - 1536, h2_r, wfc, perm, cnt[t - 1], outmax, lds);
    }
}

extern "C" void kernel_launch(void* const* d_in, const int* in_sizes, int n_in,
                              void* d_out, int out_size, void* d_ws, size_t ws_size,
                              hipStream_t stream)
{
    (void)in_sizes; (void)n_in; (void)out_size; (void)ws_size;
    const float* v     = (const float*)d_in[0];
    const float* q     = (const float*)d_in[1];
    const float* cap   = (const float*)d_in[2];
    const int*   cap_len = (const int*)d_in[3];
    const float* w_ih1 = (const float*)d_in[4];
    const float* w_hh1 = (const float*)d_in[5];
    const float* b_ih1 = (const float*)d_in[6];
    const float* b_hh1 = (const float*)d_in[7];
    const float* w_ih2 = (const float*)d_in[8];
    const float* w_hh2 = (const float*)d_in[9];
    const float* b_ih2 = (const float*)d_in[10];
    const float* b_hh2 = (const float*)d_in[11];
    const float* Wv    = (const float*)d_in[12];
    const float* Wq    = (const float*)d_in[13];
    const float* Wfc   = (const float*)d_in[14];

    float* out_max = (float*)d_out;                    // [NB, HD]
    float* alphas  = (float*)d_out + (size_t)NB * HD;  // [NB, NT, CD]

    half_t* p = (half_t*)d_ws;
    half_t* v_h    = p; p += (size_t)NB * VD;
    half_t* q_h    = p; p += (size_t)NB * QD;
    half_t* cap_h  = p; p += (size_t)NB * NT * CD;
    half_t* wih1_h = p; p += 3 * CD * CD;
    half_t* whh1_h = p; p += 3 * CD * CD;
    half_t* wih2_h = p; p += 3 * HD * CD;
    half_t* whh2_h = p; p += 3 * HD * HD;
    half_t* wfc_h  = p; p += HD * HD;
    half_t* wv_h   = p; p += CD * VD;
    half_t* wq_h   = p; p += CD * QD;
    half_t* h1b0   = p; p += (size_t)NB * CD;
    half_t* h1b1   = p; p += (size_t)NB * CD;
    half_t* h2b0   = p; p += (size_t)NB * HD;
    half_t* h2b1   = p; p += (size_t)NB * HD;
    half_t* att0   = p; p += (size_t)NB * CD;
    half_t* att1   = p; p += (size_t)NB * CD;
    float* fvq = (float*)p; p += (size_t)NB * CD * 2;
    int* perm = (int*)p;
    int* cnt  = perm + NB;

    // out_max zero (step3 fmax-RMW floor = reference's zero padding);
    // alphas zero (inactive entries are never written); h2 state zero.
    hipMemsetAsync(out_max, 0, (size_t)NB * HD * sizeof(float), stream);
    hipMemsetAsync(alphas, 0, (size_t)NB * NT * CD * sizeof(float), stream);
    hipMemsetAsync(h2b0, 0, (size_t)NB * HD * sizeof(half_t), stream);

    sort_kernel<<<1, 256, 0, stream>>>(cap_len, perm, cnt);

    CvtArgs ca;
    const float* srcs[10] = {v, q, cap, w_ih1, w_hh1, w_ih2, w_hh2, Wfc, Wv, Wq};
    half_t* dsts[10] = {v_h, q_h, cap_h, wih1_h, whh1_h, wih2_h, whh2_h, wfc_h, wv_h, wq_h};
    const int ns[10] = {NB * VD, NB * QD, NB * NT * CD, 3 * CD * CD, 3 * CD * CD,
                        3 * HD * CD, 3 * HD * HD, HD * HD, CD * VD, CD * QD};
    const int rls[10] = {VD, QD, NT * CD, 0, 0, 0, 0, 0, 0, 0};
    int acc_blk = 0;
    for (int i = 0; i < 10; ++i) {
        ca.src[i] = srcs[i]; ca.dst[i] = dsts[i]; ca.rowlen[i] = rls[i];
        ca.start[i] = acc_blk; acc_blk += ns[i] / 1024;
    }
    ca.start[10] = acc_blk;
    ca.perm = perm; ca.cnt = cnt;
    cvt_all_kernel<<<acc_blk, 256, 0, stream>>>(ca);

    // t=0: fvq + step1(0) fused (h1==0). Writes h1b1, att0, alphas[:,0,:], fvq.
    step1_0_kernel<<<512, 256, 0, stream>>>(
        v_h, wv_h, q_h, wq_h, cap_h, wih1_h, b_ih1, b_hh1,
        h1b1, fvq, cap, perm, cnt, att0, alphas);

    // t = 0..20: step2(t) || step1(t+1) || step3(t-1), guards at the edges.
    for (int t = 0; t <= NT; ++t) {
        fused321_kernel<<<2560, 256, 0, stream>>>(
            att0, att1, wih2_h, whh2_h, b_ih2, b_hh2, h2b0, h2b1,
            cap_h, wih1_h, whh1_h, b_ih1, b_hh1, h1b0, h1b1,
            fvq, cap, wfc_h, perm, cnt, out_max, alphas, t);
    }
}